// Round 7
// baseline (38937.051 us; speedup 1.0000x reference)
//
#include <hip/hip_runtime.h>
#include <stdint.h>
#include <stddef.h>

// ACT-LSTM, B=32 T=512 IN=50 H=512 OUT=66, MAX_PONDER=10, EPS=0.01, fp32.
// R18: group-multiplexed pipeline. Scope ledger closed: sc0-only races (R12),
// sc1-only races (R17), sc0sc1 correct with RTT ~5us = the phase floor
// (R13-R16, three protocol shapes all ~7us/phase). So HIDE the RTT:
//   grid = 32 blocks; block r serves ALL 8 groups round-robin (slots).
//   While group g's publish is in flight, slots g+1..g+7 compute (~4-5us)
//   -> by the time g is polled again its data landed: poll hits first try.
//   Weight slice (128 KB LDS) shared across groups; hst/pacc/xg2 reused
//   per-slot (same sync_c/sync_e hazard discipline as R16 -- proven).
//   Per-group state in registers: 8 named GState structs (no runtime
//   indexing -> no scratch); __launch_bounds__(256,1) allows 512 VGPRs.
// Protocol per group bit-identical to verified R15/R16: stamped 64B lines
// (15 payload + stamp), single-wave-instruction publish/read, sc0 sc1,
// parity pingpong depth-2 interlock, redundant all-thread decision.

#define NBLK 32

// ---------------- ws layout (float offsets) ----------------
// wh   : [0, 8388608)            512*32*512  (32 MB)
// comm : [8388608, 8429568)      2 par x 8 grp x 32 prod x 80 words
// Wp   : [8429568, 9478144)      W_hh repacked [r][k4][c][kl]  (4 MB)
// W_iT : [9478144, 9582592)      51*2048
// W_oT : [8429568, 8463360)      written by prep2_k AFTER act_main (Wp dead)
#define WS_NEED_BYTES 38434816ull

__device__ __forceinline__ float sigmf(float v) { return 1.0f / (1.0f + expf(-v)); }

// ------------------------------------------------------------------
// prep: repack weights + zero comm stamps.
__global__ void prep_k(const float* __restrict__ W_ih, const float* __restrict__ W_hh,
                       float* __restrict__ Wp, float* __restrict__ W_iT,
                       float* __restrict__ comm) {
  int idx = blockIdx.x * 256 + threadIdx.x;
  if (idx < 1048576) {
    int kl = idx & 3, c = (idx >> 2) & 63, k4 = (idx >> 8) & 127, r = idx >> 15;
    int row = (c & 3) * 512 + 16 * r + (c >> 2);
    Wp[idx] = W_hh[(size_t)row * 512 + 4 * k4 + kl];
  }
  int i2 = idx - 1048576;
  if (i2 >= 0 && i2 < 104448) {
    int col = i2 & 2047, k = i2 >> 11;
    int g = col & 3, j = col >> 2;
    W_iT[i2] = W_ih[(size_t)((g << 9) + j) * 51 + k];
  }
  int i3 = idx - 1153024;
  if (i3 >= 0 && i3 < 40960) comm[i3] = 0.0f;
}

// prep2: W_out^T into the dead Wp region (runs after act_main).
__global__ void prep2_k(const float* __restrict__ W_out, float* __restrict__ W_oT) {
  int i = blockIdx.x * 256 + threadIdx.x;
  if (i < 33792) {
    int k = i / 66, o = i - k * 66;
    W_oT[i] = W_out[(size_t)o * 512 + k];
  }
}

// per-group pipeline state (registers; named instances, never indexed)
struct GState {
  float gAcc, gxc, gxn;
  float cS, hprev, acc_h, acc_c;
  float cum0, cum1, cum2, cum3;
  float nupd, rem;
  int doneM, t, n;
  unsigned ph;
};

// ------------------------------------------------------------------
// persistent multiplexed ACT-LSTM: 32 blocks x 256 threads.
// Block r owns j in [16r,16r+16) for ALL 8 groups (group g = batches 4g..4g+3).
// comm slot (par, g, r): 80 words = 5 lines of [15 payload | stamp].
__global__ void __launch_bounds__(256, 1)
act_main(const float* __restrict__ x, const float* __restrict__ bvec,
         const float* __restrict__ W_halt, const float* __restrict__ b_halt,
         const float* __restrict__ Wp, const float* __restrict__ W_iT,
         float* __restrict__ comm, float* __restrict__ wh,
         float* __restrict__ p_out) {
  extern __shared__ __align__(16) float wl[];  // 32768 f = 128 KB: Wp slice r
  __shared__ float hst[2052];        // staged h [k][4b]; [2048] = dump slot
  __shared__ float pacc[1024];       // GEMV partials [s][c][4b]
  __shared__ float xg2[256];         // gate pre-acts [c][4b]
  __shared__ float hps2[16];         // per-wave per-batch halt partials
  __shared__ float pubf[80];         // publish staging (5 stamped lines)

  const int tid = threadIdx.x, r = blockIdx.x;
  const int c = tid & 63, w = tid >> 6, lane = tid & 63;
  const int jj = tid >> 2, bo = tid & 3;          // owner mapping (tid<64)
  const int ch = lane >> 2, b2 = lane & 3;        // halt-partial mapping

  // ---- startup: copy this rank's Wp slice into LDS (32768 floats) ----
  {
    const float* wsrc = Wp + (size_t)r * 32768;
    for (int i = tid; i < 8192; i += 256)
      *(float4*)(wl + i * 4) = *(const float4*)(wsrc + i * 4);
  }

  const float bh = b_halt[0];
  const int cg = 64 * r + c;
  const float bs = bvec[(c & 3) * 512 + 16 * r + (c >> 2)];
  const float wfc = W_iT[50 * 2048 + cg];

  // publish mapping (owner lane v=tid): line v/15, slot v%15
  const int pub_off = (tid / 15) * 16 + (tid % 15);

  // bulk word->hst mapping (per-thread constants; invalid -> dump 2048)
#define MKH(GW, DST) do { const int _q=(GW)/80, _o=(GW)%80, _li=_o>>4, _po=_o&15; \
    const int _pi = _li*15 + _po; \
    DST = ((_po < 15) && (_pi < 64)) ? (w*512 + _q*64 + _pi) : 2048; } while (0)
  int hA0,hA1,hA2,hA3,hB0,hB1,hB2,hB3;
  int hC0=2048,hC1=2048,hC2=2048,hC3=2048;
  MKH(4*lane+0,hA0); MKH(4*lane+1,hA1); MKH(4*lane+2,hA2); MKH(4*lane+3,hA3);
  MKH(256+4*lane+0,hB0); MKH(256+4*lane+1,hB1);
  MKH(256+4*lane+2,hB2); MKH(256+4*lane+3,hB3);
  if (lane < 32) {
    MKH(512+4*lane+0,hC0); MKH(512+4*lane+1,hC1);
    MKH(512+4*lane+2,hC2); MKH(512+4*lane+3,hC3);
  }
#undef MKH

  long pollbud = 4000000L;             // liveness only (shared across groups)

  // ---- per-group state init ----
#define GINIT(S, G) do { \
    S.gAcc = 0.f; S.gxn = 0.f; \
    S.gxc = bs; \
    { const float* xr = x + (size_t)((G) * 4 + w) * 512 * 50; \
      for (int k = 0; k < 50; ++k) S.gxc = fmaf(xr[k], W_iT[k * 2048 + cg], S.gxc); } \
    S.cS = 0.f; S.hprev = 0.f; S.acc_h = 0.f; S.acc_c = 0.f; \
    S.cum0 = S.cum1 = S.cum2 = S.cum3 = 0.f; \
    S.nupd = 0.f; S.rem = 0.f; \
    S.doneM = 0; S.t = 0; S.n = 0; S.ph = 0u; } while (0)

  GState s0, s1, s2, s3, s4, s5, s6, s7;
  GINIT(s0, 0); GINIT(s1, 1); GINIT(s2, 2); GINIT(s3, 3);
  GINIT(s4, 4); GINIT(s5, 5); GINIT(s6, 6); GINIT(s7, 7);
#undef GINIT

  __syncthreads();

  // ---- one pipeline slot for group g (R16 phase body, verified) ----
  auto slot = [&](GState& S, int g) {
    float val, cin = 0.f;
    if (S.ph == 0u) {
      val = S.gxc + wfc;               // fresh t=0 step: h=0 -> gemm=0
    } else {
      const unsigned par_rd = (S.ph & 1u) ^ 1u;
      const float* cb = comm + (size_t)(par_rd * 256u + g * 32 + 8 * w) * 80;
      // ---- fused poll+payload (sc0 sc1): read 40 stamped 64B lines ----
      float4 vA, vB, vC;
      vC.x = vC.y = vC.z = vC.w = 0.f;
      {
        const float* pA = cb + 4 * lane;
        const float* pB = cb + 256 + 4 * lane;
        const float* pC = cb + 512 + 4 * lane;    // lanes<32 only
        while (true) {
          asm volatile("global_load_dwordx4 %0, %1, off sc0 sc1"
                       : "=v"(vA) : "v"(pA) : "memory");
          asm volatile("global_load_dwordx4 %0, %1, off sc0 sc1"
                       : "=v"(vB) : "v"(pB) : "memory");
          if (lane < 32)
            asm volatile("global_load_dwordx4 %0, %1, off sc0 sc1"
                         : "=v"(vC) : "v"(pC) : "memory");
          asm volatile("s_waitcnt vmcnt(0)" ::: "memory");
          int ok = 1;
          if ((lane & 3) == 3) {
            ok = (__float_as_uint(vA.w) >= S.ph) && (__float_as_uint(vB.w) >= S.ph);
            if (lane < 32) ok = ok && (__float_as_uint(vC.w) >= S.ph);
          }
          if (__ballot(ok) == ~0ull) break;
          if (--pollbud < 0) break;    // liveness: degrade, never hang
          __builtin_amdgcn_s_sleep(1);
        }
      }
      // x-projection for t+1 (once per timestep)
      if (S.n == 0) {
        const int tn = (S.t + 1 > 511) ? 511 : S.t + 1;
        S.gxn = bs;
        const float* xr = x + ((size_t)(g * 4 + w) * 512 + tn) * 50;
        for (int k = 0; k < 50; ++k) S.gxn = fmaf(xr[k], W_iT[k * 2048 + cg], S.gxn);
      }
      // ---- scatter payload into hst [k][4b] (own wave region) ----
      hst[hA0] = vA.x; hst[hA1] = vA.y; hst[hA2] = vA.z; hst[hA3] = vA.w;
      hst[hB0] = vB.x; hst[hB1] = vB.y; hst[hB2] = vB.z; hst[hB3] = vB.w;
      if (lane < 32) {
        hst[hC0] = vC.x; hst[hC1] = vC.y; hst[hC2] = vC.z; hst[hC3] = vC.w;
      }

      // ---- GEMV slice: col c, 4 batches, k in [128w,+128), W from LDS ----
      {
        const float* wb = wl + w * 8192 + c * 4;
        const float* hb = hst + w * 512;
        float a0 = 0.f, a1 = 0.f, a2 = 0.f, a3 = 0.f;
        #pragma unroll 8
        for (int i = 0; i < 32; ++i) {
          const float4 wv = *(const float4*)(wb + i * 256);   // ds_read_b128
          const float4 h0 = *(const float4*)(hb + i * 16);    // wave-uniform
          const float4 h1 = *(const float4*)(hb + i * 16 + 4);
          const float4 h2v = *(const float4*)(hb + i * 16 + 8);
          const float4 h3 = *(const float4*)(hb + i * 16 + 12);
          a0 = fmaf(wv.x, h0.x, a0); a1 = fmaf(wv.x, h0.y, a1);
          a2 = fmaf(wv.x, h0.z, a2); a3 = fmaf(wv.x, h0.w, a3);
          a0 = fmaf(wv.y, h1.x, a0); a1 = fmaf(wv.y, h1.y, a1);
          a2 = fmaf(wv.y, h1.z, a2); a3 = fmaf(wv.y, h1.w, a3);
          a0 = fmaf(wv.z, h2v.x, a0); a1 = fmaf(wv.z, h2v.y, a1);
          a2 = fmaf(wv.z, h2v.z, a2); a3 = fmaf(wv.z, h2v.w, a3);
          a0 = fmaf(wv.w, h3.x, a0); a1 = fmaf(wv.w, h3.y, a1);
          a2 = fmaf(wv.w, h3.z, a2); a3 = fmaf(wv.w, h3.w, a3);
        }
        float4 pv; pv.x = a0; pv.y = a1; pv.z = a2; pv.w = a3;
        *(float4*)(pacc + w * 256 + c * 4) = pv;
      }
      // ---- halt partial + in-wave reduce: batch b2, rows ch ----
      {
        float hp = 0.f;
        #pragma unroll
        for (int i = 0; i < 8; ++i) {
          const int k = 128 * w + ch + 16 * i;
          hp = fmaf(hst[k * 4 + b2], W_halt[k], hp);
        }
        hp += __shfl_xor(hp, 4);  hp += __shfl_xor(hp, 8);
        hp += __shfl_xor(hp, 16); hp += __shfl_xor(hp, 32);
        if (lane < 4) hps2[w * 4 + lane] = hp;   // lane == b2 here
      }
      __syncthreads();   // sync_c

      const float gv = pacc[c * 4 + w] + pacc[256 + c * 4 + w] +
                       pacc[512 + c * 4 + w] + pacc[768 + c * 4 + w];
      // ---- redundant decision: every thread, all 4 batches (uniform) ----
      const float d0 = hps2[0] + hps2[4] + hps2[8] + hps2[12];
      const float d1 = hps2[1] + hps2[5] + hps2[9] + hps2[13];
      const float d2 = hps2[2] + hps2[6] + hps2[10] + hps2[14];
      const float d3 = hps2[3] + hps2[7] + hps2[11] + hps2[15];
      const float e0 = sigmf(d0 + bh), e1 = sigmf(d1 + bh);
      const float e2 = sigmf(d2 + bh), e3 = sigmf(d3 + bh);
      const int last = (S.n == 9) ? 1 : 0;
      const int ha0 = (((S.cum0 + e0) > 0.99f) | last);
      const int ha1 = (((S.cum1 + e1) > 0.99f) | last);
      const int ha2 = (((S.cum2 + e2) > 0.99f) | last);
      const int ha3 = (((S.cum3 + e3) > 0.99f) | last);
      const float q0 = (S.doneM & 1) ? 0.f : (ha0 ? (1.f - S.cum0) : e0);
      const float q1 = (S.doneM & 2) ? 0.f : (ha1 ? (1.f - S.cum1) : e1);
      const float q2 = (S.doneM & 4) ? 0.f : (ha2 ? (1.f - S.cum2) : e2);
      const float q3 = (S.doneM & 8) ? 0.f : (ha3 ? (1.f - S.cum3) : e3);
      if (tid < 4) {     // p_out bookkeeping for batch tid
        const int dmy = (S.doneM >> tid) & 1;
        const int hamy = (tid == 0) ? ha0 : (tid == 1) ? ha1 : (tid == 2) ? ha2 : ha3;
        const float cmy = (tid == 0) ? S.cum0 : (tid == 1) ? S.cum1
                        : (tid == 2) ? S.cum2 : S.cum3;
        S.nupd += dmy ? 0.f : 1.f;
        S.rem += (dmy || !hamy) ? 0.f : (1.f - cmy);
      }
      S.cum0 += (S.doneM & 1) ? 0.f : e0;  S.cum1 += (S.doneM & 2) ? 0.f : e1;
      S.cum2 += (S.doneM & 4) ? 0.f : e2;  S.cum3 += (S.doneM & 8) ? 0.f : e3;
      S.doneM |= ha0 | (ha1 << 1) | (ha2 << 2) | (ha3 << 3);
      const int alldone = (S.doneM == 15);

      const float p = (w == 0) ? q0 : (w == 1) ? q1 : (w == 2) ? q2 : q3;
      S.gAcc = fmaf(p, gv, S.gAcc);
      if (tid < 64) {    // owner accumulate (weighted h,c of staged step)
        const float po = (bo == 0) ? q0 : (bo == 1) ? q1 : (bo == 2) ? q2 : q3;
        S.acc_h = fmaf(po, S.hprev, S.acc_h);
        S.acc_c = fmaf(po, S.cS, S.acc_c);
      }
      if (alldone) {     // timestep ends; fresh step of t+1 this slot
        if (tid < 64) {
          wh[(size_t)S.t * 16384 + (size_t)(g * 4 + bo) * 512 + 16 * r + jj] = S.acc_h;
          cin = S.acc_c;
          S.acc_h = 0.f; S.acc_c = 0.f;
        }
        if (r == 0 && tid < 4)
          p_out[(size_t)(g * 4 + tid) * 512 + S.t] = S.nupd + S.rem;
        S.nupd = 0.f; S.rem = 0.f;
        S.cum0 = S.cum1 = S.cum2 = S.cum3 = 0.f; S.doneM = 0;
        val = S.gxn + wfc + S.gAcc;  // fresh gates: no GEMM (linearity)
        S.gAcc = 0.f; S.gxc = S.gxn;
        S.t += 1; S.n = 0;
        if (S.t == 512) return;      // group done (uniform) -- no publish
      } else {
        if (tid < 64) cin = S.cS;
        val = S.gxc + gv;
        S.n += 1;
      }
    }

    xg2[c * 4 + w] = val;
    __syncthreads();   // sync_e
    if (tid < 64) {    // owner (jj,bo): cell step; stage stamped publish
      const float gi = xg2[16 * jj + 0 + bo];
      const float gf = xg2[16 * jj + 4 + bo];
      const float gg = xg2[16 * jj + 8 + bo];
      const float go = xg2[16 * jj + 12 + bo];
      const float c_new = sigmf(gf) * cin + sigmf(gi) * tanhf(gg);
      const float h_new = sigmf(go) * tanhf(c_new);
      S.cS = c_new; S.hprev = h_new;
      pubf[pub_off] = h_new;
      if (tid < 5) pubf[tid * 16 + 15] = __uint_as_float(S.ph + 1u);
    }
    // wave-0-internal LDS fence, then one-instruction 5-line publish
    asm volatile("s_waitcnt lgkmcnt(0)" ::: "memory");
    __builtin_amdgcn_sched_barrier(0);
    if (tid < 40) {
      const float2 pv = *(const float2*)&pubf[2 * tid];
      float* cp = comm + (size_t)((S.ph & 1u) * 256u + g * 32 + r) * 80 + 2 * tid;
      asm volatile("global_store_dwordx2 %0, %1, off sc0 sc1"
                   :: "v"(cp), "v"(pv) : "memory");
    }
    S.ph += 1u;
  };

  // ---- superphase loop: one slot per active group ----
  while (true) {
    int any = 0;
    if (s0.t < 512) { slot(s0, 0); any = 1; }
    if (s1.t < 512) { slot(s1, 1); any = 1; }
    if (s2.t < 512) { slot(s2, 2); any = 1; }
    if (s3.t < 512) { slot(s3, 3); any = 1; }
    if (s4.t < 512) { slot(s4, 4); any = 1; }
    if (s5.t < 512) { slot(s5, 5); any = 1; }
    if (s6.t < 512) { slot(s6, 6); any = 1; }
    if (s7.t < 512) { slot(s7, 7); any = 1; }
    if (!any) break;
  }
}

// ------------------------------------------------------------------
// epilogue: out[b,t,:] = seg-softmax(wh[t,b,:] @ W_out^T + b_out)
__global__ void __launch_bounds__(256)
epi_k(const float* __restrict__ wh, const float* __restrict__ W_oT,
      const float* __restrict__ b_out, float* __restrict__ out) {
  __shared__ float hl[4][512];
  __shared__ float yl[4][66];
  const int tid = threadIdx.x, pair = tid >> 6, lane = tid & 63;
  const int bt = blockIdx.x * 4 + pair;
  const int b = bt >> 9, t = bt & 511;
  const float* hsrc = wh + (size_t)t * 16384 + (size_t)b * 512;
  *(float4*)&hl[pair][lane * 8] = *(const float4*)(hsrc + lane * 8);
  *(float4*)&hl[pair][lane * 8 + 4] = *(const float4*)(hsrc + lane * 8 + 4);
  __syncthreads();
  if (lane < 33) {
    const int o = lane * 2;
    float y0 = b_out[o], y1 = b_out[o + 1];
    const float* hp_ = hl[pair];
    #pragma unroll 8
    for (int k = 0; k < 512; ++k) {
      const float h = hp_[k];
      const float2 wv = *(const float2*)(W_oT + k * 66 + o);
      y0 = fmaf(h, wv.x, y0);
      y1 = fmaf(h, wv.y, y1);
    }
    yl[pair][o] = y0; yl[pair][o + 1] = y1;
  }
  __syncthreads();
  if (tid < 24) {
    const int pr = tid / 6, g = tid - pr * 6;
    const int bt2 = blockIdx.x * 4 + pr;
    const float* yp = &yl[pr][g * 11];
    float m = yp[0];
    for (int u = 1; u < 11; ++u) m = fmaxf(m, yp[u]);
    float e[11], ssum = 0.f;
    for (int u = 0; u < 11; ++u) { e[u] = expf(yp[u] - m); ssum += e[u]; }
    const float inv = 1.0f / ssum;
    float* op = out + (size_t)bt2 * 66 + g * 11;
    for (int u = 0; u < 11; ++u) op[u] = e[u] * inv;
  }
}

// ------------------------------------------------------------------
extern "C" void kernel_launch(void* const* d_in, const int* in_sizes, int n_in,
                              void* d_out, int out_size, void* d_ws, size_t ws_size,
                              hipStream_t stream) {
  (void)in_sizes; (void)n_in; (void)out_size;
  const float* x      = (const float*)d_in[0];
  const float* W_ih   = (const float*)d_in[1];
  const float* W_hh   = (const float*)d_in[2];
  const float* bvec   = (const float*)d_in[3];
  const float* W_out  = (const float*)d_in[4];
  const float* b_out  = (const float*)d_in[5];
  const float* W_halt = (const float*)d_in[6];
  const float* b_halt = (const float*)d_in[7];
  float* out = (float*)d_out;
  float* ws  = (float*)d_ws;

  if (ws_size < (size_t)WS_NEED_BYTES) return;  // visible failure if ws too small

  float* wh   = ws;
  float* comm = ws + 8388608;
  float* Wp   = ws + 8429568;
  float* W_iT = ws + 9478144;
  float* W_oT = ws + 8429568;     // epi-time alias of Wp (written by prep2_k)
  float* p_out = out + 1081344;   // B*T*OUT

  static int s_attr = 0;
  if (!s_attr) {
    (void)hipFuncSetAttribute((const void*)act_main,
                              hipFuncAttributeMaxDynamicSharedMemorySize, 131072);
    s_attr = 1;
  }

  hipLaunchKernelGGL(prep_k, dim3(4664), dim3(256), 0, stream,
                     W_ih, W_hh, Wp, W_iT, comm);

  void* args[9];
  args[0] = (void*)&x;      args[1] = (void*)&bvec;  args[2] = (void*)&W_halt;
  args[3] = (void*)&b_halt; args[4] = (void*)&Wp;    args[5] = (void*)&W_iT;
  args[6] = (void*)&comm;   args[7] = (void*)&wh;    args[8] = (void*)&p_out;
  hipError_t ce = hipLaunchCooperativeKernel((void*)act_main, dim3(NBLK), dim3(256),
                                             args, 131072, stream);
  if (ce != hipSuccess) {
    // fallback: plain launch (32 blocks -- trivially co-resident)
    hipLaunchKernelGGL(act_main, dim3(NBLK), dim3(256), 131072, stream,
                       x, bvec, W_halt, b_halt, Wp, W_iT, comm, wh, p_out);
  }

  hipLaunchKernelGGL(prep2_k, dim3(132), dim3(256), 0, stream, W_out, W_oT);
  hipLaunchKernelGGL(epi_k, dim3(4096), dim3(256), 0, stream, wh, W_oT, b_out, out);
}

// Round 9
// 7037.759 us; speedup vs baseline: 5.5326x; 5.5326x over previous
//
#include <hip/hip_runtime.h>
#include <stdint.h>
#include <stddef.h>

// ACT-LSTM, B=32 T=512 IN=50 H=512 OUT=66, MAX_PONDER=10, EPS=0.01, fp32.
// R20 = resubmit of R19 (container infra failed twice; no kernel verdict).
// R19 = restore of the best harness-verified kernel (R15, 7030 us).
// Session ledger: sc0-only races (R12), sc1-only races (R17), group
// multiplexing onto 32 blocks regresses 5.5x (R18, straggler-serialized).
// Structural floor: 1024 sequential GEMV+exchange steps x ~5.5us sc0sc1
// cross-XCD rendezvous (RTT + 32-block straggler jitter) + ~1.4ms compute.
//  - stamped-line publish: producer h (64 floats) -> 5 x 64B lines, each
//    [15 payload | stamp]; ONE wave store (64B line transactions atomic at
//    the MALL) -> no vmcnt ack, no flag store, no hot flag line.
//  - consumers poll 40 per-producer stamp words (scattered), then bulk-read
//    2.5 KB once into regs and scatter to LDS. Parity pingpong depth-2
//    interlock (producer <=1 phase ahead).
//  - wave-parallel halt reduce; W_hh slice in 128 KB LDS; liveness budgets;
//    coop-launch fallback; W_oT recomputed into dead Wp region after act.

#define NBLK 256

// ---------------- ws layout (float offsets) ----------------
// wh   : [0, 8388608)            512*32*512  (32 MB)
// comm : [8388608, 8429568)      2 par x 256 producers x 80 words (stamped h)
// Wp   : [8429568, 9478144)      W_hh repacked [r][k4][c][kl]  (4 MB)
// W_iT : [9478144, 9582592)      51*2048
// W_oT : [8429568, 8463360)      written by prep2_k AFTER act_main (Wp dead)
#define WS_NEED_BYTES 38434816ull

__device__ __forceinline__ float sigmf(float v) { return 1.0f / (1.0f + expf(-v)); }

// LLC-coherent load with waitcnt fused into the asm (no reorder hazard).
__device__ __forceinline__ unsigned load_llc_u(const unsigned* p) {
  unsigned v;
  asm volatile("global_load_dword %0, %1, off sc0 sc1\ns_waitcnt vmcnt(0)"
               : "=&v"(v) : "v"(p) : "memory");
  return v;
}

// ------------------------------------------------------------------
// prep: repack weights + zero comm stamps.
__global__ void prep_k(const float* __restrict__ W_ih, const float* __restrict__ W_hh,
                       float* __restrict__ Wp, float* __restrict__ W_iT,
                       float* __restrict__ comm) {
  int idx = blockIdx.x * 256 + threadIdx.x;
  if (idx < 1048576) {
    int kl = idx & 3, c = (idx >> 2) & 63, k4 = (idx >> 8) & 127, r = idx >> 15;
    int row = (c & 3) * 512 + 16 * r + (c >> 2);
    Wp[idx] = W_hh[(size_t)row * 512 + 4 * k4 + kl];
  }
  int i2 = idx - 1048576;
  if (i2 >= 0 && i2 < 104448) {
    int col = i2 & 2047, k = i2 >> 11;
    int g = col & 3, j = col >> 2;
    W_iT[i2] = W_ih[(size_t)((g << 9) + j) * 51 + k];
  }
  int i3 = idx - 1153024;
  if (i3 >= 0 && i3 < 40960) comm[i3] = 0.0f;
}

// prep2: W_out^T into the dead Wp region (runs after act_main).
__global__ void prep2_k(const float* __restrict__ W_out, float* __restrict__ W_oT) {
  int i = blockIdx.x * 256 + threadIdx.x;
  if (i < 33792) {
    int k = i / 66, o = i - k * 66;
    W_oT[i] = W_out[(size_t)o * 512 + k];
  }
}

// ------------------------------------------------------------------
// persistent ACT-LSTM: 256 blocks x 256 threads; group gid=bid>>5 (batches
// 4gid..4gid+3), rank r=bid&31 owns j in [16r,16r+16).
// comm slot for (par, gid, r): 80 words = 5 lines of [15 payload | stamp].
// Payload order = owner v=tid<64 ((jj=v>>2, bo=v&3)): pos v -> line v/15,
// slot v%15. Consumer wave w handles producers q=8w..8w+7 (640 words).
__global__ void __launch_bounds__(256)
act_main(const float* __restrict__ x, const float* __restrict__ bvec,
         const float* __restrict__ W_halt, const float* __restrict__ b_halt,
         const float* __restrict__ Wp, const float* __restrict__ W_iT,
         float* __restrict__ comm, float* __restrict__ wh,
         float* __restrict__ p_out) {
  extern __shared__ __align__(16) float wl[];  // 32768 f = 128 KB: Wp slice r
  __shared__ float hst[2052];        // staged h [k][4b]; [2048] = dump slot
  __shared__ float pacc[1024];       // GEMV partials [s][c][4b]
  __shared__ float xg2[256];         // final gate pre-acts [c][4b]
  __shared__ float hps2[16];         // per-wave per-batch halt partials
  __shared__ float pubf[80];         // publish staging (5 stamped lines)
  __shared__ float S_p[4];
  __shared__ int S_flag[1];

  const int tid = threadIdx.x, bid = blockIdx.x;
  const int gid = bid >> 5, r = bid & 31;
  const int c = tid & 63, w = tid >> 6, lane = tid & 63;
  const int jj = tid >> 2, bo = tid & 3;          // owner mapping (tid<64)
  const int ch = lane >> 2, b2 = lane & 3;        // halt-partial mapping

  // ---- startup: copy this rank's Wp slice into LDS (32768 floats) ----
  {
    const float* wsrc = Wp + (size_t)r * 32768;
    for (int i = tid; i < 8192; i += 256)
      *(float4*)(wl + i * 4) = *(const float4*)(wsrc + i * 4);
  }

  const float bh = b_halt[0];
  const int cg = 64 * r + c;
  const float bs = bvec[(c & 3) * 512 + 16 * r + (c >> 2)];
  const float wfc = W_iT[50 * 2048 + cg];

  // publish mapping (owner lane v=tid): line v/15, slot v%15
  const int pub_off = (tid / 15) * 16 + (tid % 15);
  // stamp-poll mapping (lane<40): producer q=lane/5, line j=lane%5
  const int sp_off = (lane / 5) * 80 + (lane % 5) * 16 + 15;

  // bulk word->hst mapping (per-thread constants; invalid -> dump 2048)
#define MKH(GW, DST) do { const int _q=(GW)/80, _o=(GW)%80, _li=_o>>4, _po=_o&15; \
    const int _pi = _li*15 + _po; \
    DST = ((_po < 15) && (_pi < 64)) ? (w*512 + _q*64 + _pi) : 2048; } while (0)
  int hA0,hA1,hA2,hA3,hB0,hB1,hB2,hB3;
  int hC0=2048,hC1=2048,hC2=2048,hC3=2048;
  MKH(4*lane+0,hA0); MKH(4*lane+1,hA1); MKH(4*lane+2,hA2); MKH(4*lane+3,hA3);
  MKH(256+4*lane+0,hB0); MKH(256+4*lane+1,hB1);
  MKH(256+4*lane+2,hB2); MKH(256+4*lane+3,hB3);
  if (lane < 32) {
    MKH(512+4*lane+0,hC0); MKH(512+4*lane+1,hC1);
    MKH(512+4*lane+2,hC2); MKH(512+4*lane+3,hC3);
  }
#undef MKH

  // (c,batch=w) state
  float gAcc = 0.f, gxc, gxn = 0.f;
  {  // x-projection for t=0, batch 4gid+w
    gxc = bs;
    const float* xr = x + (size_t)(gid * 4 + w) * 512 * 50;
    for (int k = 0; k < 50; ++k) gxc = fmaf(xr[k], W_iT[k * 2048 + cg], gxc);
  }
  // owner state (tid<64)
  float cS = 0.f, hprev = 0.f, acc_h = 0.f, acc_c = 0.f;
  // decision state (tid<4)
  float cum = 0.f, nupd = 0.f, rem = 0.f;
  int mydone = 0;

  int t = 0, n = 0, first = 1;
  unsigned ph = 0;
  long pollbud = 8000000L;             // liveness only; ~3 s worst case
  __syncthreads();

  while (true) {
    float val, cin = 0.f;
    if (first) {
      val = gxc + wfc;                 // phase 0: h=0 -> gemm=0
      first = 0;
    } else {
      const unsigned par_rd = (ph & 1u) ^ 1u;
      const float* cb = comm + (size_t)(par_rd * 256u + gid * 32 + 8 * w) * 80;
      // ---- stamp poll: lanes 0..39 watch 8 producers x 5 lines ----
      {
        const unsigned* stp = (const unsigned*)cb + sp_off;
        while (true) {
          unsigned sv = 0u;
          if (lane < 40) sv = load_llc_u(stp);
          if (__ballot((lane < 40) ? (sv >= ph) : 1) == ~0ull) break;
          if (--pollbud < 0) break;    // liveness: degrade, never hang
          __builtin_amdgcn_s_sleep(1);
        }
      }
      // ---- bulk read 640 words (payload+stamps) into regs ----
      float4 vA, vB, vC;
      asm volatile("global_load_dwordx4 %0, %1, off sc0 sc1"
                   : "=v"(vA) : "v"(cb + 4 * lane) : "memory");
      asm volatile("global_load_dwordx4 %0, %1, off sc0 sc1"
                   : "=v"(vB) : "v"(cb + 256 + 4 * lane) : "memory");
      if (lane < 32)
        asm volatile("global_load_dwordx4 %0, %1, off sc0 sc1"
                     : "=v"(vC) : "v"(cb + 512 + 4 * lane) : "memory");
      // under the loads: x-projection for t+1 (once per timestep)
      if (n == 0) {
        const int tn = (t + 1 > 511) ? 511 : t + 1;
        gxn = bs;
        const float* xr = x + ((size_t)(gid * 4 + w) * 512 + tn) * 50;
        for (int k = 0; k < 50; ++k) gxn = fmaf(xr[k], W_iT[k * 2048 + cg], gxn);
      }
      asm volatile("s_waitcnt vmcnt(0)" ::: "memory");
      // ---- scatter payload into hst [k][4b] (own wave region) ----
      hst[hA0] = vA.x; hst[hA1] = vA.y; hst[hA2] = vA.z; hst[hA3] = vA.w;
      hst[hB0] = vB.x; hst[hB1] = vB.y; hst[hB2] = vB.z; hst[hB3] = vB.w;
      if (lane < 32) {
        hst[hC0] = vC.x; hst[hC1] = vC.y; hst[hC2] = vC.z; hst[hC3] = vC.w;
      }

      // ---- GEMV slice: col c, 4 batches, k in [128w,+128), W from LDS ----
      {
        const float* wb = wl + w * 8192 + c * 4;
        const float* hb = hst + w * 512;
        float a0 = 0.f, a1 = 0.f, a2 = 0.f, a3 = 0.f;
        #pragma unroll 8
        for (int i = 0; i < 32; ++i) {
          const float4 wv = *(const float4*)(wb + i * 256);   // ds_read_b128
          const float4 h0 = *(const float4*)(hb + i * 16);    // wave-uniform
          const float4 h1 = *(const float4*)(hb + i * 16 + 4);
          const float4 h2v = *(const float4*)(hb + i * 16 + 8);
          const float4 h3 = *(const float4*)(hb + i * 16 + 12);
          a0 = fmaf(wv.x, h0.x, a0); a1 = fmaf(wv.x, h0.y, a1);
          a2 = fmaf(wv.x, h0.z, a2); a3 = fmaf(wv.x, h0.w, a3);
          a0 = fmaf(wv.y, h1.x, a0); a1 = fmaf(wv.y, h1.y, a1);
          a2 = fmaf(wv.y, h1.z, a2); a3 = fmaf(wv.y, h1.w, a3);
          a0 = fmaf(wv.z, h2v.x, a0); a1 = fmaf(wv.z, h2v.y, a1);
          a2 = fmaf(wv.z, h2v.z, a2); a3 = fmaf(wv.z, h2v.w, a3);
          a0 = fmaf(wv.w, h3.x, a0); a1 = fmaf(wv.w, h3.y, a1);
          a2 = fmaf(wv.w, h3.z, a2); a3 = fmaf(wv.w, h3.w, a3);
        }
        float4 pv; pv.x = a0; pv.y = a1; pv.z = a2; pv.w = a3;
        *(float4*)(pacc + w * 256 + c * 4) = pv;
      }
      // ---- halt partial + in-wave reduce: batch b2, rows ch ----
      {
        float hp = 0.f;
        #pragma unroll
        for (int i = 0; i < 8; ++i) {
          const int k = 128 * w + ch + 16 * i;
          hp = fmaf(hst[k * 4 + b2], W_halt[k], hp);
        }
        hp += __shfl_xor(hp, 4);  hp += __shfl_xor(hp, 8);
        hp += __shfl_xor(hp, 16); hp += __shfl_xor(hp, 32);
        if (lane < 4) hps2[w * 4 + lane] = hp;   // lane == b2 here
      }
      __syncthreads();   // sync_c

      const float g = pacc[c * 4 + w] + pacc[256 + c * 4 + w] +
                      pacc[512 + c * 4 + w] + pacc[768 + c * 4 + w];
      // wave 0: ACT decision for the 4 batches
      if (tid < 64) {
        int vote = 1;
        if (tid < 4) {
          const float d = hps2[tid] + hps2[4 + tid] + hps2[8 + tid] + hps2[12 + tid];
          const float halt = sigmf(d + bh);
          const int done = mydone;
          const int halted = ((cum + halt) > 0.99f) || (n == 9);
          S_p[tid] = done ? 0.f : (halted ? (1.f - cum) : halt);
          nupd += done ? 0.f : 1.f;
          rem += (done || !halted) ? 0.f : (1.f - cum);
          cum += done ? 0.f : halt;
          mydone = done | halted;
          vote = mydone;
        }
        const unsigned long long bal = __ballot(vote);
        if (tid == 0) S_flag[0] = (bal == ~0ull) ? 1 : 0;
      }
      __syncthreads();   // sync_d

      const int alldone = S_flag[0];
      const float p = S_p[w];
      gAcc = fmaf(p, g, gAcc);
      if (tid < 64) {    // owner accumulate (weighted h,c of staged step)
        const float po = S_p[bo];
        acc_h = fmaf(po, hprev, acc_h);
        acc_c = fmaf(po, cS, acc_c);
      }
      if (alldone) {     // timestep t ends; fresh step of t+1 this phase
        if (tid < 64) {
          wh[(size_t)t * 16384 + (size_t)(gid * 4 + bo) * 512 + 16 * r + jj] = acc_h;
          cin = acc_c;
          acc_h = 0.f; acc_c = 0.f;
        }
        if (r == 0 && tid < 4)
          p_out[(size_t)(gid * 4 + tid) * 512 + t] = nupd + rem;
        if (tid < 4) { cum = 0.f; nupd = 0.f; rem = 0.f; mydone = 0; }
        val = gxn + wfc + gAcc;      // fresh gates: no GEMM (linearity)
        gAcc = 0.f; gxc = gxn;
        t += 1; n = 0;
        if (t == 512) break;         // uniform within block & group
      } else {
        if (tid < 64) cin = cS;
        val = gxc + g;
        n += 1;
      }
    }

    xg2[c * 4 + w] = val;
    __syncthreads();   // sync_e
    if (tid < 64) {    // owner (jj,bo): cell step; stage stamped publish
      const float gi = xg2[16 * jj + 0 + bo];
      const float gf = xg2[16 * jj + 4 + bo];
      const float gg = xg2[16 * jj + 8 + bo];
      const float go = xg2[16 * jj + 12 + bo];
      const float c_new = sigmf(gf) * cin + sigmf(gi) * tanhf(gg);
      const float h_new = sigmf(go) * tanhf(c_new);
      cS = c_new; hprev = h_new;
      pubf[pub_off] = h_new;
      if (tid < 5) pubf[tid * 16 + 15] = __uint_as_float(ph + 1u);
    }
    // wave-0-internal LDS fence, then one-instruction 5-line publish
    asm volatile("s_waitcnt lgkmcnt(0)" ::: "memory");
    __builtin_amdgcn_sched_barrier(0);
    if (tid < 40) {
      const float2 pv = *(const float2*)&pubf[2 * tid];
      float* cp = comm + (size_t)((ph & 1u) * 256u + gid * 32 + r) * 80 + 2 * tid;
      asm volatile("global_store_dwordx2 %0, %1, off sc0 sc1"
                   :: "v"(cp), "v"(pv) : "memory");
    }
    ph += 1;
  }
}

// ------------------------------------------------------------------
// epilogue: out[b,t,:] = seg-softmax(wh[t,b,:] @ W_out^T + b_out)
__global__ void __launch_bounds__(256)
epi_k(const float* __restrict__ wh, const float* __restrict__ W_oT,
      const float* __restrict__ b_out, float* __restrict__ out) {
  __shared__ float hl[4][512];
  __shared__ float yl[4][66];
  const int tid = threadIdx.x, pair = tid >> 6, lane = tid & 63;
  const int bt = blockIdx.x * 4 + pair;
  const int b = bt >> 9, t = bt & 511;
  const float* hsrc = wh + (size_t)t * 16384 + (size_t)b * 512;
  *(float4*)&hl[pair][lane * 8] = *(const float4*)(hsrc + lane * 8);
  *(float4*)&hl[pair][lane * 8 + 4] = *(const float4*)(hsrc + lane * 8 + 4);
  __syncthreads();
  if (lane < 33) {
    const int o = lane * 2;
    float y0 = b_out[o], y1 = b_out[o + 1];
    const float* hp_ = hl[pair];
    #pragma unroll 8
    for (int k = 0; k < 512; ++k) {
      const float h = hp_[k];
      const float2 wv = *(const float2*)(W_oT + k * 66 + o);
      y0 = fmaf(h, wv.x, y0);
      y1 = fmaf(h, wv.y, y1);
    }
    yl[pair][o] = y0; yl[pair][o + 1] = y1;
  }
  __syncthreads();
  if (tid < 24) {
    const int pr = tid / 6, g = tid - pr * 6;
    const int bt2 = blockIdx.x * 4 + pr;
    const float* yp = &yl[pr][g * 11];
    float m = yp[0];
    for (int u = 1; u < 11; ++u) m = fmaxf(m, yp[u]);
    float e[11], ssum = 0.f;
    for (int u = 0; u < 11; ++u) { e[u] = expf(yp[u] - m); ssum += e[u]; }
    const float inv = 1.0f / ssum;
    float* op = out + (size_t)bt2 * 66 + g * 11;
    for (int u = 0; u < 11; ++u) op[u] = e[u] * inv;
  }
}

// ------------------------------------------------------------------
extern "C" void kernel_launch(void* const* d_in, const int* in_sizes, int n_in,
                              void* d_out, int out_size, void* d_ws, size_t ws_size,
                              hipStream_t stream) {
  (void)in_sizes; (void)n_in; (void)out_size;
  const float* x      = (const float*)d_in[0];
  const float* W_ih   = (const float*)d_in[1];
  const float* W_hh   = (const float*)d_in[2];
  const float* bvec   = (const float*)d_in[3];
  const float* W_out  = (const float*)d_in[4];
  const float* b_out  = (const float*)d_in[5];
  const float* W_halt = (const float*)d_in[6];
  const float* b_halt = (const float*)d_in[7];
  float* out = (float*)d_out;
  float* ws  = (float*)d_ws;

  if (ws_size < (size_t)WS_NEED_BYTES) return;  // visible failure if ws too small

  float* wh   = ws;
  float* comm = ws + 8388608;
  float* Wp   = ws + 8429568;
  float* W_iT = ws + 9478144;
  float* W_oT = ws + 8429568;     // epi-time alias of Wp (written by prep2_k)
  float* p_out = out + 1081344;   // B*T*OUT

  static int s_attr = 0;
  if (!s_attr) {
    (void)hipFuncSetAttribute((const void*)act_main,
                              hipFuncAttributeMaxDynamicSharedMemorySize, 131072);
    s_attr = 1;
  }

  hipLaunchKernelGGL(prep_k, dim3(4664), dim3(256), 0, stream,
                     W_ih, W_hh, Wp, W_iT, comm);

  void* args[9];
  args[0] = (void*)&x;      args[1] = (void*)&bvec;  args[2] = (void*)&W_halt;
  args[3] = (void*)&b_halt; args[4] = (void*)&Wp;    args[5] = (void*)&W_iT;
  args[6] = (void*)&comm;   args[7] = (void*)&wh;    args[8] = (void*)&p_out;
  hipError_t ce = hipLaunchCooperativeKernel((void*)act_main, dim3(NBLK), dim3(256),
                                             args, 131072, stream);
  if (ce != hipSuccess) {
    hipLaunchKernelGGL(act_main, dim3(NBLK), dim3(256), 131072, stream,
                       x, bvec, W_halt, b_halt, Wp, W_iT, comm, wh, p_out);
  }

  hipLaunchKernelGGL(prep2_k, dim3(132), dim3(256), 0, stream, W_out, W_oT);
  hipLaunchKernelGGL(epi_k, dim3(4096), dim3(256), 0, stream, wh, W_oT, b_out, out);
}